// Round 11
// baseline (248.484 us; speedup 1.0000x reference)
//
#include <hip/hip_runtime.h>
#include <hip/hip_bf16.h>

#define NPIX 4096   // H*W
#define NCH  256    // input channels
#define CI   128    // inter channels
#define EPS  1e-5f
#define SOFF 20.0f  // fixed softmax offset (cancels in normalization)

typedef unsigned short u16;
typedef __attribute__((ext_vector_type(8))) short short8;    // 8 bf16 (4 VGPRs)
typedef __attribute__((ext_vector_type(4))) float f32x4;     // 16x16 C/D
typedef __attribute__((ext_vector_type(16))) float f32x16;   // 32x32 C/D

// ---------- bf16 bit helpers ----------
__device__ __forceinline__ float bfu2f(u16 u) {
    union { unsigned int i; float f; } x; x.i = ((unsigned int)u) << 16; return x.f;
}
__device__ __forceinline__ u16 f2bfu(float f) {
    union { float ff; unsigned int i; } x; x.ff = f;
    unsigned int r = x.i + 0x7FFFu + ((x.i >> 16) & 1u);
    return (u16)(r >> 16);
}

// async global->LDS DMA, 16B per lane; dest = wave-uniform base + lane*16
__device__ __forceinline__ void gload16(const u16* g, u16* l) {
    __builtin_amdgcn_global_load_lds(
        (const __attribute__((address_space(1))) unsigned int*)g,
        (__attribute__((address_space(3))) unsigned int*)l,
        16, 0, 0);
}

// =====================================================================
// Kernel 0: merged weight prep (unchanged).
// =====================================================================
__global__ __launch_bounds__(256) void prep_kernel(
    const float* __restrict__ w_v,
    const float* __restrict__ w_k1, const float* __restrict__ w_q1,
    const float* __restrict__ w_k2, const float* __restrict__ w_q2,
    const float* __restrict__ w_ts, const float* __restrict__ w_tq,
    u16* __restrict__ Wbf,
    const float* __restrict__ w_cat, u16* __restrict__ wT)
{
    const int bx = blockIdx.x;
    if (bx < 768) {
        int idx = bx * 256 + threadIdx.x;
        int src = idx / 98304;
        int r   = idx - src * 98304;
        int o   = r >> 8, c = r & 255;
        float v;
        if (o < 128)      v = w_v[(size_t)o * 256 + c];
        else if (o < 192) v = (src ? w_k2 : w_k1)[(size_t)(o - 128) * 256 + c];
        else if (o < 256) v = (src ? w_q2 : w_q1)[(size_t)(o - 192) * 256 + c];
        else              v = (src ? w_ts : w_tq)[(size_t)(o - 256) * 256 + c];
        Wbf[idx] = f2bfu(v);
    } else {
        int co = bx - 768;
        const float* srcb = w_cat + (size_t)co * 2304;
        u16* dstb = wT + (size_t)co * 2304;
        for (int t = threadIdx.x; t < 2304; t += 256) {
            int ic = t / 9, tap = t - ic * 9;
            dstb[tap * 256 + ic] = f2bfu(srcb[t]);
        }
    }
}

// =====================================================================
// Kernel 1: MFMA proj GEMM (unchanged).
// =====================================================================
__global__ __launch_bounds__(256) void proj2_kernel(
    const float* __restrict__ xq, const float* __restrict__ xs,
    const u16* __restrict__ Wbf,
    const float* __restrict__ b_v,
    const float* __restrict__ b_k1, const float* __restrict__ b_q1,
    const float* __restrict__ b_k2, const float* __restrict__ b_q2,
    const float* __restrict__ b_ts, const float* __restrict__ g_ts,
    const float* __restrict__ be_ts, const float* __restrict__ m_ts,
    const float* __restrict__ v_ts,
    const float* __restrict__ b_tq, const float* __restrict__ g_tq,
    const float* __restrict__ be_tq, const float* __restrict__ m_tq,
    const float* __restrict__ v_tq,
    u16* __restrict__ kT, u16* __restrict__ qT,
    u16* __restrict__ vq, u16* __restrict__ vs,
    u16* __restrict__ tq, u16* __restrict__ ts)
{
    __shared__ u16 Xs[64 * 264];
    __shared__ u16 KQ[64 * 136];

    const int tid  = threadIdx.x;
    const int lane = tid & 63;
    const int wid  = tid >> 6;
    const int l16  = lane & 15;
    const int quad = lane >> 4;

    const int n0  = blockIdx.x * 64;
    const int bz  = blockIdx.z;
    const int b   = bz >> 1, src = bz & 1;

    const float* xg = (src ? xs : xq) + (size_t)b * NCH * NPIX + n0;
    #pragma unroll
    for (int k0 = 0; k0 < 64; k0 += 16) {
        float v[16];
        #pragma unroll
        for (int k = 0; k < 16; ++k) {
            int idx = tid + (k0 + k) * 256;
            int c = idx >> 6, n = idx & 63;
            v[k] = xg[(size_t)c * NPIX + n];
        }
        #pragma unroll
        for (int k = 0; k < 16; ++k) {
            int idx = tid + (k0 + k) * 256;
            int c = idx >> 6, n = idx & 63;
            Xs[n * 264 + c] = f2bfu(v[k]);
        }
    }
    __syncthreads();

    const u16* W = Wbf + (size_t)src * 384 * 256;
    const int o0w = wid * 96;
    const float* bk = src ? b_k2 : b_k1;
    const float* bq = src ? b_q2 : b_q1;
    const float* bt = src ? b_ts : b_tq;

    f32x4 acc[24];
    #pragma unroll
    for (int ot = 0; ot < 6; ++ot) {
        int ob = o0w + ot * 16 + quad * 4;
        const float* bp;
        if (ob < 128)      bp = b_v + ob;
        else if (ob < 192) bp = bk + (ob - 128);
        else if (ob < 256) bp = bq + (ob - 192);
        else               bp = bt + (ob - 256);
        float4 b4 = *(const float4*)bp;
        f32x4 iv = (f32x4){b4.x, b4.y, b4.z, b4.w};
        #pragma unroll
        for (int pt = 0; pt < 4; ++pt) acc[ot * 4 + pt] = iv;
    }

    #pragma unroll
    for (int kc = 0; kc < 8; ++kc) {
        short8 bfr[4];
        #pragma unroll
        for (int pt = 0; pt < 4; ++pt)
            bfr[pt] = *(const short8*)&Xs[(pt * 16 + l16) * 264 + kc * 32 + quad * 8];
        #pragma unroll
        for (int ot = 0; ot < 6; ++ot) {
            short8 a = *(const short8*)&W[(size_t)(o0w + ot * 16 + l16) * 256 + kc * 32 + quad * 8];
            #pragma unroll
            for (int pt = 0; pt < 4; ++pt)
                acc[ot * 4 + pt] = __builtin_amdgcn_mfma_f32_16x16x32_bf16(a, bfr[pt], acc[ot * 4 + pt], 0, 0, 0);
        }
    }

    #pragma unroll
    for (int ot = 0; ot < 6; ++ot) {
        int ob = o0w + ot * 16;
        #pragma unroll
        for (int pt = 0; pt < 4; ++pt) {
            int px = pt * 16 + l16;
            f32x4 v4 = acc[ot * 4 + pt];
            if (ob < 128) {
                u16* dst = src ? vs : vq;
                #pragma unroll
                for (int r = 0; r < 4; ++r)
                    dst[((size_t)b * CI + ob + quad * 4 + r) * NPIX + n0 + px] = f2bfu(v4[r]);
            } else if (ob < 256) {
                int colb = (ob < 192) ? (ob - 128) : (64 + ob - 192);
                #pragma unroll
                for (int r = 0; r < 4; ++r)
                    KQ[px * 136 + colb + quad * 4 + r] = f2bfu(v4[r]);
            } else {
                const float* g  = src ? g_ts  : g_tq;
                const float* be = src ? be_ts : be_tq;
                const float* mm = src ? m_ts  : m_tq;
                const float* vv = src ? v_ts  : v_tq;
                u16* dst = src ? ts : tq;
                #pragma unroll
                for (int r = 0; r < 4; ++r) {
                    int oc = ob - 256 + quad * 4 + r;
                    float inv = g[oc] * rsqrtf(vv[oc] + EPS);
                    dst[((size_t)b * CI + oc) * NPIX + n0 + px] =
                        f2bfu((v4[r] - mm[oc]) * inv + be[oc]);
                }
            }
        }
    }
    __syncthreads();

    const int chb = src ? 64 : 0;
    #pragma unroll
    for (int u = 0; u < 4; ++u) {
        int idx = tid + u * 256;
        int px = idx >> 4, oct = idx & 15;
        uint4 val = *(const uint4*)&KQ[px * 136 + oct * 8];
        if (oct < 8)
            *(uint4*)&kT[((size_t)b * NPIX + n0 + px) * CI + chb + oct * 8] = val;
        else
            *(uint4*)&qT[((size_t)b * NPIX + n0 + px) * CI + chb + (oct - 8) * 8] = val;
    }
}

// =====================================================================
// Kernel 2: dual flash attention, split-m, async-DMA double buffer,
// 32x32x16 MFMA for BOTH S and PV (2x FLOP per LDS fragment read).
// Wave w: S: q-rows (w>>1)*32..+31 x m-half (w&1)*32..+31 (8 MFMA,
// 8 A-reads). PV: q-rows (w>>1)*32 x ch-half (w&1)*64 (8 MFMA, 12
// reads). P m-dim spans wave pairs -> one barrier between softmax
// and PV. L accumulated per-wave, cross-wave combined once at end.
// =====================================================================
#define AKS_OFF 0
#define AVT_OFF 16384
#define APS_OFF 32768
#define ASMEM_U16 37376

__global__ __launch_bounds__(256, 2) void attn_kernel(
    const u16* __restrict__ kT, const u16* __restrict__ qT,
    const u16* __restrict__ vq, const u16* __restrict__ vs,
    u16* __restrict__ Opart, float* __restrict__ Lpart, int nseg)
{
    __shared__ __align__(16) u16 smem[ASMEM_U16];
    __shared__ float Lbuf[2][2][32];
    u16* Ps = smem + APS_OFF;   // [q-row 64][m 64 + pad8] stride 72

    const int tid  = threadIdx.x;
    const int lane = tid & 63;
    const int wid  = tid >> 6;
    const int l32  = lane & 31;
    const int hi   = lane >> 5;          // k-half selector
    const int rg   = wid >> 1;           // row group (32 q-rows)
    const int mh   = wid & 1;            // m-half for S
    const int chb  = (wid & 1) * 64;     // ch-half for PV
    const int rows0 = rg * 32;

    const int nt = blockIdx.x;
    const int n0 = nt * 64;
    const int at = blockIdx.y;
    const int z  = blockIdx.z;
    const int b  = z / nseg;
    const int seg = z - b * nseg;

    const u16* Qg = at ? qT : kT;
    const u16* Kg = at ? kT : qT;
    const u16* Vg = at ? vq : vs;

    // Q fragments (B-operand for S^T 32x32x16), direct from global
    short8 qf[8];
    {
        const u16* Qb = Qg + ((size_t)b * NPIX + n0 + rows0 + l32) * CI;
        #pragma unroll
        for (int kc = 0; kc < 8; ++kc)
            qf[kc] = *(const short8*)&Qb[kc * 16 + hi * 8];
    }

    f32x16 o2[2];
    #pragma unroll
    for (int ct = 0; ct < 2; ++ct)
        #pragma unroll
        for (int i = 0; i < 16; ++i) o2[ct][i] = 0.f;
    float Lacc = 0.f;

    const u16* KgB = Kg + (size_t)b * NPIX * CI;
    const u16* VgB = Vg + (size_t)b * CI * NPIX;

    const int mt0 = seg * (64 / nseg);
    const int mt1 = mt0 + (64 / nseg);

    #define ISSUE_TILE(buf, m0_)                                              \
    {                                                                         \
        u16* kb_ = smem + AKS_OFF + (buf) * 8192;                             \
        u16* vb_ = smem + AVT_OFF + (buf) * 8192;                             \
        _Pragma("unroll")                                                     \
        for (int k = 0; k < 4; ++k) {                                         \
            int sb  = k * 256 + wid * 64;                                     \
            int idx = sb + lane;                                              \
            int row = idx >> 4, segp = idx & 15;                              \
            int segg = segp ^ (row & 15);                                     \
            gload16(KgB + (size_t)((m0_) + row) * CI + segg * 8, kb_ + sb * 8); \
        }                                                                     \
        _Pragma("unroll")                                                     \
        for (int k = 0; k < 4; ++k) {                                         \
            int sb  = k * 256 + wid * 64;                                     \
            int idx = sb + lane;                                              \
            int c = idx >> 3, sgp = idx & 7;                                  \
            int sgg = sgp ^ (c & 7);                                          \
            gload16(VgB + (size_t)c * NPIX + (m0_) + sgg * 8, vb_ + sb * 8);  \
        }                                                                     \
    }

    int cur = 0;
    ISSUE_TILE(0, mt0 * 64);

    for (int mt = mt0; mt < mt1; ++mt) {
        __syncthreads();   // tile mt landed; prev buf free
        if (mt + 1 < mt1) ISSUE_TILE(1 - cur, (mt + 1) * 64);

        const u16* Ks = smem + AKS_OFF + cur * 8192;
        const u16* Vt = smem + AVT_OFF + cur * 8192;

        // ---- S^T 32x32: A = K[m = mh*32+l32][k], B = Q (regs) ----
        f32x16 sv;
        #pragma unroll
        for (int i = 0; i < 16; ++i) sv[i] = 0.f;
        {
            const int row = mh * 32 + l32;
            #pragma unroll
            for (int kc = 0; kc < 8; ++kc) {
                int sg = (kc * 2 + hi) ^ (row & 15);
                short8 kf = *(const short8*)&Ks[row * 128 + sg * 8];
                sv = __builtin_amdgcn_mfma_f32_32x32x16_bf16(kf, qf[kc], sv, 0, 0, 0);
            }
        }

        // ---- no-max softmax; lane owns m = mh*32 + rq*8 + hi*4 + 0..3
        //      for q-row rows0 + l32 (col = lane&31) ----
        float Ls = 0.f;
        u16* myPs = Ps + (rows0 + l32) * 72 + mh * 32;
        #pragma unroll
        for (int rq = 0; rq < 4; ++rq) {
            float p0 = __expf(sv[rq * 4 + 0] - SOFF);
            float p1 = __expf(sv[rq * 4 + 1] - SOFF);
            float p2 = __expf(sv[rq * 4 + 2] - SOFF);
            float p3 = __expf(sv[rq * 4 + 3] - SOFF);
            Ls += (p0 + p1) + (p2 + p3);
            ushort4 pk;
            pk.x = f2bfu(p0); pk.y = f2bfu(p1);
            pk.z = f2bfu(p2); pk.w = f2bfu(p3);
            *(ushort4*)&myPs[rq * 8 + hi * 4] = pk;
        }
        Ls += __shfl_xor(Ls, 32);
        Lacc += Ls;
        __syncthreads();   // Ps visible to partner wave (m-halves join)

        // ---- PV 32x32: D[ch][qrow]; A = V^T (LDS), B = P (LDS) ----
        short8 pf[4];
        #pragma unroll
        for (int kc = 0; kc < 4; ++kc)
            pf[kc] = *(const short8*)&Ps[(rows0 + l32) * 72 + kc * 16 + hi * 8];
        #pragma unroll
        for (int ct = 0; ct < 2; ++ct) {
            const int c = chb + ct * 32 + l32;
            #pragma unroll
            for (int kc = 0; kc < 4; ++kc) {
                int slot = (kc * 2 + hi) ^ (c & 7);
                short8 vf = *(const short8*)&Vt[c * 64 + slot * 8];
                o2[ct] = __builtin_amdgcn_mfma_f32_32x32x16_bf16(vf, pf[kc], o2[ct], 0, 0, 0);
            }
        }
        cur ^= 1;
    }

    // ---- store partials: O[row][ch] bf16 + per-row L ----
    const size_t tile = (((size_t)(at * 2 + b) * 64 + nt) * nseg + seg);
    u16* Ob = Opart + tile * 8192;
    {
        const int row = rows0 + l32;
        #pragma unroll
        for (int ct = 0; ct < 2; ++ct) {
            #pragma unroll
            for (int rq = 0; rq < 4; ++rq) {
                ushort4 pk;
                pk.x = f2bfu(o2[ct][rq * 4 + 0]);
                pk.y = f2bfu(o2[ct][rq * 4 + 1]);
                pk.z = f2bfu(o2[ct][rq * 4 + 2]);
                pk.w = f2bfu(o2[ct][rq * 4 + 3]);
                *(ushort4*)&Ob[row * 128 + chb + ct * 32 + rq * 8 + hi * 4] = pk;
            }
        }
    }
    if (hi == 0) Lbuf[rg][mh][l32] = Lacc;
    __syncthreads();
    if (mh == 0 && hi == 0)
        Lpart[tile * 64 + rows0 + l32] = Lbuf[rg][0][l32] + Lbuf[rg][1][l32];
    #undef ISSUE_TILE
}

// =====================================================================
// Kernel 2b: combine split-m partials + epilogue; Ebf store coalesced
// via two-pass (r-major for out, c-major for Ebf).
// =====================================================================
__global__ __launch_bounds__(256) void attn_combine_kernel(
    const u16* __restrict__ Opart, const float* __restrict__ Lpart,
    const u16* __restrict__ tq, const u16* __restrict__ ts,
    const float* __restrict__ scale_p,
    float* __restrict__ out, u16* __restrict__ Ebf, int nseg)
{
    __shared__ float Of[128 * 68];
    __shared__ float invL[64];

    const int tid = threadIdx.x;
    const int nt = blockIdx.x;
    const int n0 = nt * 64;
    const int at = blockIdx.y;
    const int b  = blockIdx.z;

    const u16* Tg = at ? tq : ts;
    float* outE   = out + (size_t)(at ? 1 : 2) * 1048576;
    const int ch0 = at ? 0 : 128;
    const size_t tbase = ((size_t)(at * 2 + b) * 64 + nt) * nseg;

    if (tid < 64) {
        float Lg = 0.f;
        for (int s = 0; s < nseg; ++s) Lg += Lpart[(tbase + s) * 64 + tid];
        invL[tid] = 1.f / Lg;
    }
    __syncthreads();

    #pragma unroll
    for (int k = 0; k < 4; ++k) {
        int idx = tid + k * 256;
        int row = idx >> 4, oct = idx & 15;
        float m[8] = {0.f, 0.f, 0.f, 0.f, 0.f, 0.f, 0.f, 0.f};
        for (int s = 0; s < nseg; ++s) {
            union { uint4 v; u16 u[8]; } pk;
            pk.v = *(const uint4*)&Opart[(tbase + s) * 8192 + row * 128 + oct * 8];
            #pragma unroll
            for (int j = 0; j < 8; ++j) m[j] += bfu2f(pk.u[j]);
        }
        float w = invL[row];
        #pragma unroll
        for (int j = 0; j < 8; ++j)
            Of[(oct * 8 + j) * 68 + row] = m[j] * w;
    }
    __syncthreads();

    float scale = *scale_p;
    const u16* Tb = Tg + (size_t)b * CI * NPIX + n0;
    float* Ob = outE + (size_t)b * CI * NPIX + n0;
    // pass 1: fp32 out (r-coalesced); fold scale + t back into Of
    for (int idx = tid; idx < 128 * 64; idx += 256) {
        int c = idx >> 6, r = idx & 63;
        float v = scale * Of[c * 68 + r] + bfu2f(Tb[(size_t)c * NPIX + r]);
        Ob[(size_t)c * NPIX + r] = v;
        Of[c * 68 + r] = v;
    }
    __syncthreads();
    // pass 2: Ebf (c-coalesced, 128B contiguous per wave)
    u16* Eb = Ebf + ((size_t)b * NPIX + n0) * NCH + ch0;
    for (int idx = tid; idx < 128 * 64; idx += 256) {
        int r = idx >> 7, c = idx & 127;
        Eb[(size_t)r * NCH + c] = f2bfu(Of[c * 68 + r]);
    }
}

// =====================================================================
// Kernel 3: 3x3 conv MFMA implicit GEMM, barrier-free private staging
// (unchanged from round 10).
// =====================================================================
#define CXT_STR 40

__global__ __launch_bounds__(256) void conv_kernel(
    const u16* __restrict__ Ebf,
    const u16* __restrict__ wT,
    const float* __restrict__ g_cat, const float* __restrict__ be_cat,
    const float* __restrict__ m_cat, const float* __restrict__ v_cat,
    float* __restrict__ out)
{
    __shared__ u16 XtW[4][3 * 34 * CXT_STR];

    const int tid  = threadIdx.x;
    const int lane = tid & 63;
    const int wid  = tid >> 6;
    const int l16  = lane & 15;
    const int quad = lane >> 4;

    const int h    = blockIdx.x;
    const int coff = blockIdx.y * 32;
    const int b    = blockIdx.z;

    const int cot = wid >> 1;
    const int pxt = (wid & 1) * 2;
    const int gc0 = pxt * 16 - 1;

    f32x4 acc[2];
    #pragma unroll
    for (int j = 0; j < 2; ++j) acc[j] = (f32x4){0.f, 0.f, 0.f, 0.f};

    const u16* Eb = Ebf + (size_t)b * NPIX * NCH;
    u16* Xw = &XtW[wid][0];
    const int cobase = coff + cot * 16 + l16;

    for (int icc = 0; icc < 8; ++icc) {
        const int ic0 = icc * 32;

        short8 wfrag[9];
        #pragma unroll
        for (int tap = 0; tap < 9; ++tap)
            wfrag[tap] = *(const short8*)&wT[((size_t)cobase * 9 + tap) * 256 + ic0 + quad * 8];

        for (int u = lane; u < 408; u += 64) {
            int part = u & 3, xe = u >> 2;
            int dh = xe / 34, x = xe - dh * 34;
            int gr = h + dh - 1, gc = gc0 + x;
            uint4 val = make_uint4(0u, 0u, 0u, 0u);
            if ((unsigned)gr < 64u && (unsigned)gc < 64u)
                val = *(const uint4*)&Eb[((size_t)gr * 64 + gc) * NCH + ic0 + part * 8];
            *(uint4*)&Xw[(dh * 34 + x) * CXT_STR + part * 8] = val;
        }

        #pragma unroll
        for (int tap = 0; tap < 9; ++tap) {
            const int dh = tap / 3, dw = tap % 3;
            short8 bf[2];
            #pragma unroll
            for (int j = 0; j < 2; ++j) {
                int x = j * 16 + l16 + dw;
                bf[j] = *(const short8*)&Xw[(dh * 34 + x) * CXT_STR + quad * 8];
            }
            #pragma unroll
            for (int j = 0; j < 2; ++j)
                acc[j] = __builtin_amdgcn_mfma_f32_16x16x32_bf16(wfrag[tap], bf[j], acc[j], 0, 0, 0);
        }
    }

    #pragma unroll
    for (int r = 0; r < 4; ++r) {
        int co = coff + cot * 16 + quad * 4 + r;
        float inv = g_cat[co] * rsqrtf(v_cat[co] + EPS);
        float mm  = m_cat[co];
        float be  = be_cat[co];
        #pragma unroll
        for (int j = 0; j < 2; ++j) {
            int wcol = (pxt + j) * 16 + l16;
            float v = (acc[j][r] - mm) * inv + be;
            out[((size_t)b * CI + co) * NPIX + h * 64 + wcol] = fmaxf(v, 0.f);
        }
    }
}

// =====================================================================
extern "C" void kernel_launch(void* const* d_in, const int* in_sizes, int n_in,
                              void* d_out, int out_size, void* d_ws, size_t ws_size,
                              hipStream_t stream)
{
    const float* q     = (const float*)d_in[0];
    const float* s     = (const float*)d_in[1];
    const float* scale = (const float*)d_in[2];
    const float* w_v   = (const float*)d_in[3];
    const float* b_v   = (const float*)d_in[4];
    const float* w_k1  = (const float*)d_in[5];
    const float* b_k1  = (const float*)d_in[6];
    const float* w_q1  = (const float*)d_in[7];
    const float* b_q1  = (const float*)d_in[8];
    const float* w_k2  = (const float*)d_in[9];
    const float* b_k2  = (const float*)d_in[10];
    const float* w_q2  = (const float*)d_in[11];
    const float* b_q2  = (const float*)d_in[12];
    const float* w_ts  = (const float*)d_in[13];
    const float* b_ts  = (const float*)d_in[14];
    const float* g_ts  = (const float*)d_in[15];
    const float* be_ts = (const float*)d_in[16];
    const float* m_ts  = (const float*)d_in[17];
    const float* v_ts  = (const float*)d_in[18];
    const float* w_tq  = (const float*)d_in[19];
    const float* b_tq  = (const float*)d_in[20];
    const float* g_tq  = (const float*)d_in[21];
    const float* be_tq = (const float*)d_in[22];
    const float* m_tq  = (const float*)d_in[23];
    const float* v_tq  = (const float*)d_in[24];
    const float* w_cat = (const float*)d_in[25];
    const float* g_cat = (const float*)d_in[26];
    const float* be_cat= (const float*)d_in[27];
    const float* m_cat = (const float*)d_in[28];
    const float* v_cat = (const float*)d_in[29];

    float* out = (float*)d_out;
    u16* ws = (u16*)d_ws;
    const size_t SZ = (size_t)2 * CI * NPIX;        // 1,048,576 u16 per buffer
    u16* kT  = ws;
    u16* qT  = kT + SZ;
    u16* vq  = qT + SZ;
    u16* vs  = vq + SZ;
    u16* tq  = vs + SZ;
    u16* ts  = tq + SZ;
    u16* Wbf = ts + SZ;
    u16* B   = Wbf + 196608;
    u16* Ebf = B;
    u16* wTc = B + 2097152;
    u16* Opart = wTc + 294912;

    const size_t fixed_u16 = 6 * SZ + 196608 + 2097152 + 294912;
    int nseg = 1;
    {
        size_t need4 = (fixed_u16 + (size_t)4 * 2097152) * 2 + (size_t)4 * 131072;
        size_t need2 = (fixed_u16 + (size_t)2 * 2097152) * 2 + (size_t)2 * 131072;
        if (ws_size >= need4)      nseg = 4;
        else if (ws_size >= need2) nseg = 2;
    }
    float* Lpart = (float*)(Opart + (size_t)nseg * 256 * 8192);

    dim3 blk(256);
    hipLaunchKernelGGL(prep_kernel, dim3(896), blk, 0, stream,
                       w_v, w_k1, w_q1, w_k2, w_q2, w_ts, w_tq, Wbf, w_cat, wTc);
    hipLaunchKernelGGL(proj2_kernel, dim3(64, 1, 4), blk, 0, stream,
                       q, s, Wbf, b_v, b_k1, b_q1, b_k2, b_q2,
                       b_ts, g_ts, be_ts, m_ts, v_ts,
                       b_tq, g_tq, be_tq, m_tq, v_tq,
                       kT, qT, vq, vs, tq, ts);
    hipLaunchKernelGGL(attn_kernel, dim3(64, 2, 2 * nseg), blk, 0, stream,
                       kT, qT, vq, vs, Opart, Lpart, nseg);
    hipLaunchKernelGGL(attn_combine_kernel, dim3(64, 2, 2), blk, 0, stream,
                       Opart, Lpart, tq, ts, scale, out, Ebf, nseg);
    hipLaunchKernelGGL(conv_kernel, dim3(64, 4, 2), blk, 0, stream,
                       Ebf, wTc, g_cat, be_cat, m_cat, v_cat, out);
}

// Round 12
// 243.203 us; speedup vs baseline: 1.0217x; 1.0217x over previous
//
#include <hip/hip_runtime.h>
#include <hip/hip_bf16.h>

#define NPIX 4096   // H*W
#define NCH  256    // input channels
#define CI   128    // inter channels
#define EPS  1e-5f
#define SOFF 20.0f  // fixed softmax offset (cancels in normalization)

typedef unsigned short u16;
typedef __attribute__((ext_vector_type(8))) short short8;   // 8 bf16 (4 VGPRs)
typedef __attribute__((ext_vector_type(4))) float f32x4;    // MFMA C/D

// ---------- bf16 bit helpers ----------
__device__ __forceinline__ float bfu2f(u16 u) {
    union { unsigned int i; float f; } x; x.i = ((unsigned int)u) << 16; return x.f;
}
__device__ __forceinline__ u16 f2bfu(float f) {
    union { float ff; unsigned int i; } x; x.ff = f;
    unsigned int r = x.i + 0x7FFFu + ((x.i >> 16) & 1u);
    return (u16)(r >> 16);
}

// async global->LDS DMA, 16B per lane; dest = wave-uniform base + lane*16
__device__ __forceinline__ void gload16(const u16* g, u16* l) {
    __builtin_amdgcn_global_load_lds(
        (const __attribute__((address_space(1))) unsigned int*)g,
        (__attribute__((address_space(3))) unsigned int*)l,
        16, 0, 0);
}

// =====================================================================
// Kernel 0: merged weight prep (unchanged).
// =====================================================================
__global__ __launch_bounds__(256) void prep_kernel(
    const float* __restrict__ w_v,
    const float* __restrict__ w_k1, const float* __restrict__ w_q1,
    const float* __restrict__ w_k2, const float* __restrict__ w_q2,
    const float* __restrict__ w_ts, const float* __restrict__ w_tq,
    u16* __restrict__ Wbf,
    const float* __restrict__ w_cat, u16* __restrict__ wT)
{
    const int bx = blockIdx.x;
    if (bx < 768) {
        int idx = bx * 256 + threadIdx.x;
        int src = idx / 98304;
        int r   = idx - src * 98304;
        int o   = r >> 8, c = r & 255;
        float v;
        if (o < 128)      v = w_v[(size_t)o * 256 + c];
        else if (o < 192) v = (src ? w_k2 : w_k1)[(size_t)(o - 128) * 256 + c];
        else if (o < 256) v = (src ? w_q2 : w_q1)[(size_t)(o - 192) * 256 + c];
        else              v = (src ? w_ts : w_tq)[(size_t)(o - 256) * 256 + c];
        Wbf[idx] = f2bfu(v);
    } else {
        int co = bx - 768;
        const float* srcb = w_cat + (size_t)co * 2304;
        u16* dstb = wT + (size_t)co * 2304;
        for (int t = threadIdx.x; t < 2304; t += 256) {
            int ic = t / 9, tap = t - ic * 9;
            dstb[tap * 256 + ic] = f2bfu(srcb[t]);
        }
    }
}

// =====================================================================
// Kernel 1: MFMA proj GEMM, o-dim split across 2 blocks for occupancy.
// Grid (64, 2, 4): y = o-half (192 ch), z = (b,src). 43 KB LDS -> 2/CU.
// oh=0: v(0..127) + k(128..191); oh=1: q(192..255) + t(256..383).
// =====================================================================
__global__ __launch_bounds__(256) void proj2_kernel(
    const float* __restrict__ xq, const float* __restrict__ xs,
    const u16* __restrict__ Wbf,
    const float* __restrict__ b_v,
    const float* __restrict__ b_k1, const float* __restrict__ b_q1,
    const float* __restrict__ b_k2, const float* __restrict__ b_q2,
    const float* __restrict__ b_ts, const float* __restrict__ g_ts,
    const float* __restrict__ be_ts, const float* __restrict__ m_ts,
    const float* __restrict__ v_ts,
    const float* __restrict__ b_tq, const float* __restrict__ g_tq,
    const float* __restrict__ be_tq, const float* __restrict__ m_tq,
    const float* __restrict__ v_tq,
    u16* __restrict__ kT, u16* __restrict__ qT,
    u16* __restrict__ vq, u16* __restrict__ vs,
    u16* __restrict__ tq, u16* __restrict__ ts)
{
    __shared__ u16 Xs[64 * 264];
    __shared__ u16 KQ[64 * 72];     // 64 px x 64 cols (+8 pad)

    const int tid  = threadIdx.x;
    const int lane = tid & 63;
    const int wid  = tid >> 6;
    const int l16  = lane & 15;
    const int quad = lane >> 4;

    const int n0  = blockIdx.x * 64;
    const int oh  = blockIdx.y;
    const int bz  = blockIdx.z;
    const int b   = bz >> 1, src = bz & 1;

    // ---- stage x tile: coalesced fp32 reads, transpose into Xs[n][c] ----
    const float* xg = (src ? xs : xq) + (size_t)b * NCH * NPIX + n0;
    #pragma unroll
    for (int k0 = 0; k0 < 64; k0 += 16) {
        float v[16];
        #pragma unroll
        for (int k = 0; k < 16; ++k) {
            int idx = tid + (k0 + k) * 256;
            int c = idx >> 6, n = idx & 63;
            v[k] = xg[(size_t)c * NPIX + n];
        }
        #pragma unroll
        for (int k = 0; k < 16; ++k) {
            int idx = tid + (k0 + k) * 256;
            int c = idx >> 6, n = idx & 63;
            Xs[n * 264 + c] = f2bfu(v[k]);
        }
    }
    __syncthreads();

    const u16* W = Wbf + (size_t)src * 384 * 256;
    const int o0w = oh * 192 + wid * 48;
    const float* bk = src ? b_k2 : b_k1;
    const float* bq = src ? b_q2 : b_q1;
    const float* bt = src ? b_ts : b_tq;

    f32x4 acc[12];
    #pragma unroll
    for (int ot = 0; ot < 3; ++ot) {
        int ob = o0w + ot * 16 + quad * 4;
        const float* bp;
        if (ob < 128)      bp = b_v + ob;
        else if (ob < 192) bp = bk + (ob - 128);
        else if (ob < 256) bp = bq + (ob - 192);
        else               bp = bt + (ob - 256);
        float4 b4 = *(const float4*)bp;
        f32x4 iv = (f32x4){b4.x, b4.y, b4.z, b4.w};
        #pragma unroll
        for (int pt = 0; pt < 4; ++pt) acc[ot * 4 + pt] = iv;
    }

    #pragma unroll
    for (int kc = 0; kc < 8; ++kc) {
        short8 bfr[4];
        #pragma unroll
        for (int pt = 0; pt < 4; ++pt)
            bfr[pt] = *(const short8*)&Xs[(pt * 16 + l16) * 264 + kc * 32 + quad * 8];
        #pragma unroll
        for (int ot = 0; ot < 3; ++ot) {
            short8 a = *(const short8*)&W[(size_t)(o0w + ot * 16 + l16) * 256 + kc * 32 + quad * 8];
            #pragma unroll
            for (int pt = 0; pt < 4; ++pt)
                acc[ot * 4 + pt] = __builtin_amdgcn_mfma_f32_16x16x32_bf16(a, bfr[pt], acc[ot * 4 + pt], 0, 0, 0);
        }
    }

    #pragma unroll
    for (int ot = 0; ot < 3; ++ot) {
        int ob = o0w + ot * 16;
        #pragma unroll
        for (int pt = 0; pt < 4; ++pt) {
            int px = pt * 16 + l16;
            f32x4 v4 = acc[ot * 4 + pt];
            if (ob < 128) {
                u16* dst = src ? vs : vq;
                #pragma unroll
                for (int r = 0; r < 4; ++r)
                    dst[((size_t)b * CI + ob + quad * 4 + r) * NPIX + n0 + px] = f2bfu(v4[r]);
            } else if (ob < 256) {
                int colb = (ob < 192) ? (ob - 128) : (ob - 192);
                #pragma unroll
                for (int r = 0; r < 4; ++r)
                    KQ[px * 72 + colb + quad * 4 + r] = f2bfu(v4[r]);
            } else {
                const float* g  = src ? g_ts  : g_tq;
                const float* be = src ? be_ts : be_tq;
                const float* mm = src ? m_ts  : m_tq;
                const float* vv = src ? v_ts  : v_tq;
                u16* dst = src ? ts : tq;
                #pragma unroll
                for (int r = 0; r < 4; ++r) {
                    int oc = ob - 256 + quad * 4 + r;
                    float inv = g[oc] * rsqrtf(vv[oc] + EPS);
                    dst[((size_t)b * CI + oc) * NPIX + n0 + px] =
                        f2bfu((v4[r] - mm[oc]) * inv + be[oc]);
                }
            }
        }
    }
    __syncthreads();

    // cooperative store of this block's 64 KQ cols (oh=0 -> kT, oh=1 -> qT)
    u16* KQdst = oh ? qT : kT;
    const int chb = src ? 64 : 0;
    #pragma unroll
    for (int u = 0; u < 2; ++u) {
        int idx = tid + u * 256;          // 512 units: 64 px x 8 octs
        int px = idx >> 3, oct = idx & 7;
        uint4 val = *(const uint4*)&KQ[px * 72 + oct * 8];
        *(uint4*)&KQdst[((size_t)b * NPIX + n0 + px) * CI + chb + oct * 8] = val;
    }
}

// =====================================================================
// Kernel 2: dual flash attention (round-10 version, verbatim revert):
// 16x16 S^T form, split-m, async-DMA double buffer, no-max softmax,
// intra-wave Ps (one barrier per iter).
// =====================================================================
#define AKS_OFF 0
#define AVT_OFF 16384
#define APS_OFF 32768
#define ASMEM_U16 37376

__global__ __launch_bounds__(256) void attn_kernel(
    const u16* __restrict__ kT, const u16* __restrict__ qT,
    const u16* __restrict__ vq, const u16* __restrict__ vs,
    u16* __restrict__ Opart, float* __restrict__ Lpart, int nseg)
{
    __shared__ __align__(16) u16 smem[ASMEM_U16];
    u16* Ps = smem + APS_OFF;   // [q-row 64][m 64 + pad8] stride 72

    const int tid  = threadIdx.x;
    const int lane = tid & 63;
    const int wid  = tid >> 6;
    const int l16  = lane & 15;
    const int quad = lane >> 4;
    const int strip = wid * 16;

    const int nt = blockIdx.x;
    const int n0 = nt * 64;
    const int at = blockIdx.y;
    const int z  = blockIdx.z;
    const int b  = z / nseg;
    const int seg = z - b * nseg;

    const u16* Qg = at ? qT : kT;
    const u16* Kg = at ? kT : qT;
    const u16* Vg = at ? vq : vs;

    short8 qf[4];
    {
        const u16* Qb = Qg + ((size_t)b * NPIX + n0 + strip + l16) * CI;
        #pragma unroll
        for (int kc = 0; kc < 4; ++kc)
            qf[kc] = *(const short8*)&Qb[kc * 32 + quad * 8];
    }

    f32x4 o[8];
    #pragma unroll
    for (int ct = 0; ct < 8; ++ct) o[ct] = (f32x4){0.f, 0.f, 0.f, 0.f};
    float L = 0.f;

    const u16* KgB = Kg + (size_t)b * NPIX * CI;
    const u16* VgB = Vg + (size_t)b * CI * NPIX;

    const int mt0 = seg * (64 / nseg);
    const int mt1 = mt0 + (64 / nseg);

    #define ISSUE_TILE(buf, m0_)                                              \
    {                                                                         \
        u16* kb_ = smem + AKS_OFF + (buf) * 8192;                             \
        u16* vb_ = smem + AVT_OFF + (buf) * 8192;                             \
        _Pragma("unroll")                                                     \
        for (int k = 0; k < 4; ++k) {                                         \
            int sb  = k * 256 + wid * 64;                                     \
            int idx = sb + lane;                                              \
            int row = idx >> 4, segp = idx & 15;                              \
            int segg = segp ^ (row & 15);                                     \
            gload16(KgB + (size_t)((m0_) + row) * CI + segg * 8, kb_ + sb * 8); \
        }                                                                     \
        _Pragma("unroll")                                                     \
        for (int k = 0; k < 4; ++k) {                                         \
            int sb  = k * 256 + wid * 64;                                     \
            int idx = sb + lane;                                              \
            int c = idx >> 3, sgp = idx & 7;                                  \
            int sgg = sgp ^ (c & 7);                                          \
            gload16(VgB + (size_t)c * NPIX + (m0_) + sgg * 8, vb_ + sb * 8);  \
        }                                                                     \
    }

    int cur = 0;
    ISSUE_TILE(0, mt0 * 64);

    for (int mt = mt0; mt < mt1; ++mt) {
        __syncthreads();   // vmcnt(0) drain: tile mt landed; prev buf free
        if (mt + 1 < mt1) ISSUE_TILE(1 - cur, (mt + 1) * 64);

        const u16* Ks = smem + AKS_OFF + cur * 8192;
        const u16* Vt = smem + AVT_OFF + cur * 8192;

        // ---- S^T = K Q^T : A = K rows (LDS), B = Q (regs) ----
        f32x4 sv[4];
        #pragma unroll
        for (int m2 = 0; m2 < 4; ++m2) {
            f32x4 c = (f32x4){0.f, 0.f, 0.f, 0.f};
            #pragma unroll
            for (int kc = 0; kc < 4; ++kc) {
                int s = kc * 4 + quad;
                short8 kf = *(const short8*)&Ks[(m2 * 16 + l16) * 128 + ((s ^ l16) * 8)];
                c = __builtin_amdgcn_mfma_f32_16x16x32_bf16(kf, qf[kc], c, 0, 0, 0);
            }
            sv[m2] = c;
        }

        // ---- no-max softmax: lane owns 4 consecutive m for row strip+l16 ----
        float Lsum = 0.f;
        u16* myPs = Ps + (strip + l16) * 72;
        #pragma unroll
        for (int m2 = 0; m2 < 4; ++m2) {
            float p0 = __expf(sv[m2][0] - SOFF);
            float p1 = __expf(sv[m2][1] - SOFF);
            float p2 = __expf(sv[m2][2] - SOFF);
            float p3 = __expf(sv[m2][3] - SOFF);
            Lsum += (p0 + p1) + (p2 + p3);
            ushort4 pk;
            pk.x = f2bfu(p0); pk.y = f2bfu(p1);
            pk.z = f2bfu(p2); pk.w = f2bfu(p3);
            *(ushort4*)&myPs[m2 * 16 + quad * 4] = pk;
        }
        Lsum += __shfl_xor(Lsum, 16);
        Lsum += __shfl_xor(Lsum, 32);
        L += Lsum;

        // ---- PV (Ps rows [strip,strip+16) intra-wave: no barrier) ----
        short8 ap[2];
        #pragma unroll
        for (int kc = 0; kc < 2; ++kc)
            ap[kc] = *(const short8*)&Ps[(strip + l16) * 72 + kc * 32 + quad * 8];
        #pragma unroll
        for (int ct = 0; ct < 8; ++ct) {
            #pragma unroll
            for (int kc = 0; kc < 2; ++kc) {
                int s = kc * 4 + quad;
                short8 bv = *(const short8*)&Vt[(ct * 16 + l16) * 64 + ((s ^ (l16 & 7)) * 8)];
                o[ct] = __builtin_amdgcn_mfma_f32_16x16x32_bf16(ap[kc], bv, o[ct], 0, 0, 0);
            }
        }
        cur ^= 1;
    }

    const size_t tile = (((size_t)(at * 2 + b) * 64 + nt) * nseg + seg);
    u16* Ob = Opart + tile * 8192;
    #pragma unroll
    for (int r = 0; r < 4; ++r) {
        int row = strip + quad * 4 + r;
        #pragma unroll
        for (int ct = 0; ct < 8; ++ct)
            Ob[row * 128 + ct * 16 + l16] = f2bfu(o[ct][r]);
    }
    if (quad == 0)
        Lpart[tile * 64 + strip + l16] = L;
    #undef ISSUE_TILE
}

// =====================================================================
// Kernel 2b: combine split-m partials + epilogue, row-half split
// (grid 128x2x2 = 512 -> 2 blocks/CU). Coalesced Ebf pass kept.
// =====================================================================
__global__ __launch_bounds__(256) void attn_combine_kernel(
    const u16* __restrict__ Opart, const float* __restrict__ Lpart,
    const u16* __restrict__ tq, const u16* __restrict__ ts,
    const float* __restrict__ scale_p,
    float* __restrict__ out, u16* __restrict__ Ebf, int nseg)
{
    __shared__ float Of[128 * 36];   // [ch][row 32 + pad4]
    __shared__ float invL[32];

    const int tid = threadIdx.x;
    const int bx  = blockIdx.x;
    const int nt  = bx >> 1;
    const int rh  = bx & 1;
    const int n0  = nt * 64;
    const int r0  = rh * 32;
    const int at  = blockIdx.y;
    const int b   = blockIdx.z;

    const u16* Tg = at ? tq : ts;
    float* outE   = out + (size_t)(at ? 1 : 2) * 1048576;
    const int ch0 = at ? 0 : 128;
    const size_t tbase = ((size_t)(at * 2 + b) * 64 + nt) * nseg;

    if (tid < 32) {
        float Lg = 0.f;
        for (int s = 0; s < nseg; ++s) Lg += Lpart[(tbase + s) * 64 + r0 + tid];
        invL[tid] = 1.f / Lg;
    }
    __syncthreads();

    #pragma unroll
    for (int k = 0; k < 2; ++k) {
        int idx = tid + k * 256;             // 512 units: 32 rows x 16 octs
        int rl = idx >> 4, oct = idx & 15;
        float m[8] = {0.f, 0.f, 0.f, 0.f, 0.f, 0.f, 0.f, 0.f};
        for (int s = 0; s < nseg; ++s) {
            union { uint4 v; u16 u[8]; } pk;
            pk.v = *(const uint4*)&Opart[(tbase + s) * 8192 + (r0 + rl) * 128 + oct * 8];
            #pragma unroll
            for (int j = 0; j < 8; ++j) m[j] += bfu2f(pk.u[j]);
        }
        float w = invL[rl];
        #pragma unroll
        for (int j = 0; j < 8; ++j)
            Of[(oct * 8 + j) * 36 + rl] = m[j] * w;
    }
    __syncthreads();

    float scale = *scale_p;
    const u16* Tb = Tg + (size_t)b * CI * NPIX + n0 + r0;
    float* Ob = outE + (size_t)b * CI * NPIX + n0 + r0;
    // pass 1: fp32 out (r-coalesced); fold scale + t back into Of
    for (int idx = tid; idx < 128 * 32; idx += 256) {
        int c = idx >> 5, rl = idx & 31;
        float v = scale * Of[c * 36 + rl] + bfu2f(Tb[(size_t)c * NPIX + rl]);
        Ob[(size_t)c * NPIX + rl] = v;
        Of[c * 36 + rl] = v;
    }
    __syncthreads();
    // pass 2: Ebf (c-coalesced)
    u16* Eb = Ebf + ((size_t)b * NPIX + n0 + r0) * NCH + ch0;
    for (int idx = tid; idx < 128 * 32; idx += 256) {
        int rl = idx >> 7, c = idx & 127;
        Eb[(size_t)rl * NCH + c] = f2bfu(Of[c * 36 + rl]);
    }
}

// =====================================================================
// Kernel 3: 3x3 conv MFMA implicit GEMM, barrier-free private staging,
// co split 32->16 (grid 64x8x2 = 1024 -> 4 blocks/CU). Wave w handles
// px quarter w*16..+15 with private 3x18 halo.
// =====================================================================
#define CXT_STR 40

__global__ __launch_bounds__(256) void conv_kernel(
    const u16* __restrict__ Ebf,
    const u16* __restrict__ wT,
    const float* __restrict__ g_cat, const float* __restrict__ be_cat,
    const float* __restrict__ m_cat, const float* __restrict__ v_cat,
    float* __restrict__ out)
{
    __shared__ u16 XtW[4][3 * 18 * CXT_STR];

    const int tid  = threadIdx.x;
    const int lane = tid & 63;
    const int wid  = tid >> 6;
    const int l16  = lane & 15;
    const int quad = lane >> 4;

    const int h    = blockIdx.x;
    const int co0  = blockIdx.y * 16;
    const int b    = blockIdx.z;

    const int gc0 = wid * 16 - 1;         // global col of local x=0

    f32x4 acc = (f32x4){0.f, 0.f, 0.f, 0.f};

    const u16* Eb = Ebf + (size_t)b * NPIX * NCH;
    u16* Xw = &XtW[wid][0];
    const int cobase = co0 + l16;

    for (int icc = 0; icc < 8; ++icc) {
        const int ic0 = icc * 32;

        short8 wfrag[9];
        #pragma unroll
        for (int tap = 0; tap < 9; ++tap)
            wfrag[tap] = *(const short8*)&wT[((size_t)cobase * 9 + tap) * 256 + ic0 + quad * 8];

        // private staging: 3 rows x 18 cols x 4 parts = 216 uint4 per wave
        for (int u = lane; u < 216; u += 64) {
            int part = u & 3, xe = u >> 2;       // xe 0..53
            int dh = xe / 18, x = xe - dh * 18;  // x 0..17
            int gr = h + dh - 1, gc = gc0 + x;
            uint4 val = make_uint4(0u, 0u, 0u, 0u);
            if ((unsigned)gr < 64u && (unsigned)gc < 64u)
                val = *(const uint4*)&Eb[((size_t)gr * 64 + gc) * NCH + ic0 + part * 8];
            *(uint4*)&Xw[(dh * 18 + x) * CXT_STR + part * 8] = val;
        }

        #pragma unroll
        for (int tap = 0; tap < 9; ++tap) {
            const int dh = tap / 3, dw = tap % 3;
            short8 bf = *(const short8*)&Xw[(dh * 18 + l16 + dw) * CXT_STR + quad * 8];
            acc = __builtin_amdgcn_mfma_f32_16x16x32_bf16(wfrag[tap], bf, acc, 0, 0, 0);
        }
    }

    #pragma unroll
    for (int r = 0; r < 4; ++r) {
        int co = co0 + quad * 4 + r;
        float inv = g_cat[co] * rsqrtf(v_cat[co] + EPS);
        float mm  = m_cat[co];
        float be  = be_cat[co];
        int wcol = wid * 16 + l16;
        float v = (acc[r] - mm) * inv + be;
        out[((size_t)b * CI + co) * NPIX + h * 64 + wcol] = fmaxf(v, 0.f);
    }
}

// =====================================================================
extern "C" void kernel_launch(void* const* d_in, const int* in_sizes, int n_in,
                              void* d_out, int out_size, void* d_ws, size_t ws_size,
                              hipStream_t stream)
{
    const float* q     = (const float*)d_in[0];
    const float* s     = (const float*)d_in[1];
    const float* scale = (const float*)d_in[2];
    const float* w_v   = (const float*)d_in[3];
    const float* b_v   = (const float*)d_in[4];
    const float* w_k1  = (const float*)d_in[5];
    const float* b_k1  = (const float*)d_in[6];
    const float* w_q1  = (const float*)d_in[7];
    const float* b_q1  = (const float*)d_in[8];
    const float* w_k2  = (const float*)d_in[9];
    const float* b_k2  = (const float*)d_in[10];
    const float* w_q2  = (const float*)d_in[11];
    const float* b_q2  = (const float*)d_in[12];
    const float* w_ts  = (const float*)d_in[13];
    const float* b_ts  = (const float*)d_in[14];
    const float* g_ts  = (const float*)d_in[15];
    const float* be_ts = (const float*)d_in[16];
    const float* m_ts  = (const float*)d_in[17];
    const float* v_ts  = (const float*)d_in[18];
    const float* w_tq  = (const float*)d_in[19];
    const float* b_tq  = (const float*)d_in[20];
    const float* g_tq  = (const float*)d_in[21];
    const float* be_tq = (const float*)d_in[22];
    const float* m_tq  = (const float*)d_in[23];
    const float* v_tq  = (const float*)d_in[24];
    const float* w_cat = (const float*)d_in[25];
    const float* g_cat = (const float*)d_in[26];
    const float* be_cat= (const float*)d_in[27];
    const float* m_cat = (const float*)d_in[28];
    const float* v_cat = (const float*)d_in[29];

    float* out = (float*)d_out;
    u16* ws = (u16*)d_ws;
    const size_t SZ = (size_t)2 * CI * NPIX;        // 1,048,576 u16 per buffer
    u16* kT  = ws;
    u16* qT  = kT + SZ;
    u16* vq  = qT + SZ;
    u16* vs  = vq + SZ;
    u16* tq  = vs + SZ;
    u16* ts  = tq + SZ;
    u16* Wbf = ts + SZ;
    u16* B   = Wbf + 196608;
    u16* Ebf = B;
    u16* wTc = B + 2097152;
    u16* Opart = wTc + 294912;

    const size_t fixed_u16 = 6 * SZ + 196608 + 2097152 + 294912;
    int nseg = 1;
    {
        size_t need4 = (fixed_u16 + (size_t)4 * 2097152) * 2 + (size_t)4 * 131072;
        size_t need2 = (fixed_u16 + (size_t)2 * 2097152) * 2 + (size_t)2 * 131072;
        if (ws_size >= need4)      nseg = 4;
        else if (ws_size >= need2) nseg = 2;
    }
    float* Lpart = (float*)(Opart + (size_t)nseg * 256 * 8192);

    dim3 blk(256);
    hipLaunchKernelGGL(prep_kernel, dim3(896), blk, 0, stream,
                       w_v, w_k1, w_q1, w_k2, w_q2, w_ts, w_tq, Wbf, w_cat, wTc);
    hipLaunchKernelGGL(proj2_kernel, dim3(64, 2, 4), blk, 0, stream,
                       q, s, Wbf, b_v, b_k1, b_q1, b_k2, b_q2,
                       b_ts, g_ts, be_ts, m_ts, v_ts,
                       b_tq, g_tq, be_tq, m_tq, v_tq,
                       kT, qT, vq, vs, tq, ts);
    hipLaunchKernelGGL(attn_kernel, dim3(64, 2, 2 * nseg), blk, 0, stream,
                       kT, qT, vq, vs, Opart, Lpart, nseg);
    hipLaunchKernelGGL(attn_combine_kernel, dim3(128, 2, 2), blk, 0, stream,
                       Opart, Lpart, tq, ts, scale, out, Ebf, nseg);
    hipLaunchKernelGGL(conv_kernel, dim3(64, 8, 2), blk, 0, stream,
                       Ebf, wTc, g_cat, be_cat, m_cat, v_cat, out);
}